// Round 4
// baseline (264.002 us; speedup 1.0000x reference)
//
#include <hip/hip_runtime.h>
#include <stdint.h>

// Problem constants (B=2, L=2048, D=2048, E=8, Dg=256, k=2)
#define T_TOK 4096
#define DIM   2048
#define NEXP  8
#define DG    256
#define TOPK  2

// GEMM tiling: block tile 64(M) x 128(N), BKU=64, 4 waves of 32x64 each.
#define BM 64
#define BN 128
#define BKU 64
#define NROWS  (T_TOK*TOPK + NEXP*BM)   // 8704 padded row capacity
#define NBLK_M (NROWS/BM)               // 136 M-blocks
#define KSPLIT 4                        // down GEMM K-split (occupancy 1->4.25/CU)

typedef __attribute__((ext_vector_type(8))) short short8;
typedef __attribute__((ext_vector_type(8))) float float8;
typedef __attribute__((ext_vector_type(4))) float f32x4;

static __device__ __forceinline__ short f2bf(float f) {
    union { float f; uint32_t u; } v{f};
    uint32_t r = v.u + 0x7fffu + ((v.u >> 16) & 1u);   // RNE
    return (short)(r >> 16);
}
static __device__ __forceinline__ float b2f(short s) {
    union { uint32_t u; float f; } v{((uint32_t)(unsigned short)s) << 16};
    return v.f;
}

#define GLD16(g, l) \
    __builtin_amdgcn_global_load_lds((const __attribute__((address_space(1))) void*)(g), \
                                     (__attribute__((address_space(3))) void*)(l), 16, 0, 0)

// ---------------------------------------------------------------------------
// Fused front kernel. Blocks [0,1024): gate (one wave per token).
// Blocks [1024, 9216): weight fp32->bf16 (256 float4 each, exact cover).
// Blocks [9216, 11808): zero-init of out (fp32) and dr (fp32 accumulator) --
// both are atomically accumulated into later, and this kernel precedes all
// GEMMs in stream order.
// ---------------------------------------------------------------------------
__global__ __launch_bounds__(256) void gateconv_kernel(const float* __restrict__ x,
                                                       const float* __restrict__ Wg,
                                                       const float* __restrict__ Wd,
                                                       const float* __restrict__ Wu,
                                                       int* __restrict__ gidx,
                                                       float* __restrict__ gval,
                                                       short* __restrict__ x_bf,
                                                       short* __restrict__ Wd_bf,
                                                       short* __restrict__ Wu_bf,
                                                       float* __restrict__ out,
                                                       float* __restrict__ dr)
{
    if (blockIdx.x >= 9216) {
        // ---- zero region: out (2097152 float4) then dr (557056 float4) ----
        int z = blockIdx.x - 9216;                  // 0..2591
        float4 zero = {0.f, 0.f, 0.f, 0.f};
#pragma unroll
        for (int q = 0; q < 4; q++) {
            int i = z * 1024 + q * 256 + threadIdx.x;
            if (i < 2097152) ((float4*)out)[i] = zero;
            else             ((float4*)dr)[i - 2097152] = zero;
        }
        return;
    }
    if (blockIdx.x >= 1024) {
        // ---- convW path ----
        const int n4 = NEXP * DG * DIM / 4;               // 1048576 per tensor
        int i = (blockIdx.x - 1024) * 256 + threadIdx.x;  // < 2*n4 exactly
        const float* s; short* d; int j;
        if (i < n4) { s = Wd; d = Wd_bf; j = i; }
        else        { s = Wu; d = Wu_bf; j = i - n4; }
        float4 v = ((const float4*)s)[j];
        short4 o;
        o.x = f2bf(v.x); o.y = f2bf(v.y); o.z = f2bf(v.z); o.w = f2bf(v.w);
        ((short4*)d)[j] = o;
        return;
    }

    // ---- gate path ----
    int token = blockIdx.x * 4 + (threadIdx.x >> 6);
    int lane  = threadIdx.x & 63;
    const float4* xr = (const float4*)(x + (size_t)token * DIM);

    float4 xv[8];
#pragma unroll
    for (int i = 0; i < 8; i++) xv[i] = xr[lane + 64 * i];

    short4* xb = (short4*)(x_bf + (size_t)token * DIM);
#pragma unroll
    for (int i = 0; i < 8; i++) {
        short4 o;
        o.x = f2bf(xv[i].x); o.y = f2bf(xv[i].y);
        o.z = f2bf(xv[i].z); o.w = f2bf(xv[i].w);
        xb[lane + 64 * i] = o;
    }

    float acc[NEXP];
#pragma unroll
    for (int e = 0; e < NEXP; e++) {
        const float4* wr = (const float4*)(Wg + e * DIM);
        float a = 0.0f;
#pragma unroll
        for (int i = 0; i < 8; i++) {
            float4 w = wr[lane + 64 * i];
            a += xv[i].x * w.x + xv[i].y * w.y + xv[i].z * w.z + xv[i].w * w.w;
        }
        acc[e] = a;
    }

#pragma unroll
    for (int m = 1; m < 64; m <<= 1) {
#pragma unroll
        for (int e = 0; e < NEXP; e++) acc[e] += __shfl_xor(acc[e], m, 64);
    }

    if (lane == 0) {
        float sg[NEXP];
#pragma unroll
        for (int e = 0; e < NEXP; e++) sg[e] = 1.0f / (1.0f + expf(-acc[e]));
        int i0 = 0;
#pragma unroll
        for (int e = 1; e < NEXP; e++) if (sg[e] > sg[i0]) i0 = e;   // strict >: lowest index wins
        int i1 = (i0 == 0) ? 1 : 0;
#pragma unroll
        for (int e = 0; e < NEXP; e++) if (e != i0 && e != i1 && sg[e] > sg[i1]) i1 = e;
        gidx[2 * token + 0] = i0;
        gidx[2 * token + 1] = i1;
        gval[2 * token + 0] = sg[i0];
        gval[2 * token + 1] = sg[i1];
    }
}

// ---------------------------------------------------------------------------
// Bucket rows by expert (segments padded to BM). Ballot-based counting and
// mask-prefix scatter. Also emits per-ROW gate grow[pos] for the up-GEMM's
// fused output-combine epilogue.
// ---------------------------------------------------------------------------
__global__ __launch_bounds__(1024) void bucket_kernel(const int* __restrict__ gidx,
                                                      const float* __restrict__ gval,
                                                      int* __restrict__ rowtok,
                                                      int* __restrict__ rowpos,
                                                      float* __restrict__ grow,
                                                      int* __restrict__ seg_off)
{
    __shared__ int cnt[NEXP];
    __shared__ int cur[NEXP];
    int tid = threadIdx.x, lane = tid & 63;
    if (tid < NEXP) cnt[tid] = 0;
    __syncthreads();

    int e_[8];
#pragma unroll
    for (int r = 0; r < 8; r++) e_[r] = gidx[r * 1024 + tid];

    int mycnt = 0;
#pragma unroll
    for (int r = 0; r < 8; r++) {
        int e = e_[r];
#pragma unroll
        for (int ee = 0; ee < NEXP; ee++) {
            unsigned long long m = __ballot(e == ee);
            if (lane == ee) mycnt += (int)__popcll(m);
        }
    }
    if (lane < NEXP) atomicAdd(&cnt[lane], mycnt);
    __syncthreads();

    if (tid == 0) {
        int o = 0;
        for (int e = 0; e < NEXP; e++) {
            seg_off[e] = o;
            cur[e] = o;
            o += ((cnt[e] + BM - 1) / BM) * BM;
        }
        seg_off[NEXP] = o;
    }
    __syncthreads();

    for (int r = tid; r < NROWS; r += 1024) rowtok[r] = -1;
    __syncthreads();

#pragma unroll
    for (int r = 0; r < 8; r++) {
        int idx = r * 1024 + tid;
        int e = e_[r];
#pragma unroll
        for (int ee = 0; ee < NEXP; ee++) {
            unsigned long long m = __ballot(e == ee);
            if (m == 0) continue;                       // wave-uniform
            int leader = __ffsll((unsigned long long)m) - 1;
            int base = 0;
            if (lane == leader) base = atomicAdd(&cur[ee], (int)__popcll(m));
            base = __shfl(base, leader, 64);
            if (e == ee) {
                int pos = base + (int)__popcll(m & ((1ull << lane) - 1ull));
                rowtok[pos] = idx >> 1;
                rowpos[idx] = pos;
                grow[pos] = gval[idx];
            }
        }
    }
}

// ---------------------------------------------------------------------------
// Down GEMM (bf16 MFMA), counted-vmcnt double-buffer, K-SPLIT x4:
// grid = 136M x 2N x 4K = 1088 blocks (4.25/CU). Each block computes a
// partial sum over K/4=512 and fp32-atomicAdd's into dr (zeroed upstream).
// ---------------------------------------------------------------------------
#define AS3 __attribute__((address_space(3)))

#define VMCNT(N) asm volatile("s_waitcnt vmcnt(" #N ")" ::: "memory")
#define BAR()    __builtin_amdgcn_s_barrier()

#define STAGE(B_) do { \
    GLD16(agA0, lA_##B_##_0); \
    GLD16(agA1, lA_##B_##_1); \
    GLD16(agB0, lB_##B_##_0); \
    GLD16(agB1, lB_##B_##_1); \
    GLD16(agB2, lB_##B_##_2); \
    GLD16(agB3, lB_##B_##_3); \
    agA0 += BKU; agA1 += BKU; \
    agB0 += BKU; agB1 += BKU; agB2 += BKU; agB3 += BKU; \
} while (0)

#define COMP(B_) do { \
    short8 a00 = *(const short8*)&As[B_][am0][c0]; \
    short8 a10 = *(const short8*)&As[B_][am1][c0]; \
    short8 b00 = *(const short8*)&Bs[B_][bn0][c0]; \
    short8 b10 = *(const short8*)&Bs[B_][bn1][c0]; \
    short8 b20 = *(const short8*)&Bs[B_][bn2][c0]; \
    short8 b30 = *(const short8*)&Bs[B_][bn3][c0]; \
    short8 a01 = *(const short8*)&As[B_][am0][c1]; \
    short8 a11 = *(const short8*)&As[B_][am1][c1]; \
    short8 b01 = *(const short8*)&Bs[B_][bn0][c1]; \
    short8 b11 = *(const short8*)&Bs[B_][bn1][c1]; \
    short8 b21 = *(const short8*)&Bs[B_][bn2][c1]; \
    short8 b31 = *(const short8*)&Bs[B_][bn3][c1]; \
    acc[0][0] = __builtin_amdgcn_mfma_f32_16x16x32_bf16(a00, b00, acc[0][0], 0, 0, 0); \
    acc[0][1] = __builtin_amdgcn_mfma_f32_16x16x32_bf16(a00, b10, acc[0][1], 0, 0, 0); \
    acc[0][2] = __builtin_amdgcn_mfma_f32_16x16x32_bf16(a00, b20, acc[0][2], 0, 0, 0); \
    acc[0][3] = __builtin_amdgcn_mfma_f32_16x16x32_bf16(a00, b30, acc[0][3], 0, 0, 0); \
    acc[1][0] = __builtin_amdgcn_mfma_f32_16x16x32_bf16(a10, b00, acc[1][0], 0, 0, 0); \
    acc[1][1] = __builtin_amdgcn_mfma_f32_16x16x32_bf16(a10, b10, acc[1][1], 0, 0, 0); \
    acc[1][2] = __builtin_amdgcn_mfma_f32_16x16x32_bf16(a10, b20, acc[1][2], 0, 0, 0); \
    acc[1][3] = __builtin_amdgcn_mfma_f32_16x16x32_bf16(a10, b30, acc[1][3], 0, 0, 0); \
    acc[0][0] = __builtin_amdgcn_mfma_f32_16x16x32_bf16(a01, b01, acc[0][0], 0, 0, 0); \
    acc[0][1] = __builtin_amdgcn_mfma_f32_16x16x32_bf16(a01, b11, acc[0][1], 0, 0, 0); \
    acc[0][2] = __builtin_amdgcn_mfma_f32_16x16x32_bf16(a01, b21, acc[0][2], 0, 0, 0); \
    acc[0][3] = __builtin_amdgcn_mfma_f32_16x16x32_bf16(a01, b31, acc[0][3], 0, 0, 0); \
    acc[1][0] = __builtin_amdgcn_mfma_f32_16x16x32_bf16(a11, b01, acc[1][0], 0, 0, 0); \
    acc[1][1] = __builtin_amdgcn_mfma_f32_16x16x32_bf16(a11, b11, acc[1][1], 0, 0, 0); \
    acc[1][2] = __builtin_amdgcn_mfma_f32_16x16x32_bf16(a11, b21, acc[1][2], 0, 0, 0); \
    acc[1][3] = __builtin_amdgcn_mfma_f32_16x16x32_bf16(a11, b31, acc[1][3], 0, 0, 0); \
} while (0)

__global__ __launch_bounds__(256) void gemm_down_kernel(const short* __restrict__ A,
                                                        const short* __restrict__ B,
                                                        const int* __restrict__ rowtok,
                                                        const int* __restrict__ seg_off,
                                                        float* __restrict__ dr)
{
    constexpr int K = DIM, Ntot = DG;
    constexpr int KCHUNK = K / KSPLIT;     // 512
    __shared__ __align__(16) short As[2][BM][BKU];   // 16 KB
    __shared__ __align__(16) short Bs[2][BN][BKU];   // 32 KB

    int d  = blockIdx.x;
    int ks = d / 272;                      // K-chunk id (0..3)
    int q  = d % 272;
    int lid = (q & 7) * 34 + (q >> 3);     // XCD pairing within a K-chunk
    int bx = lid >> 1, by = lid & 1;

    int row0 = bx * BM;
    int total = seg_off[NEXP];
    if (row0 >= total) return;
    int e = 0;
    while (row0 >= seg_off[e + 1]) ++e;   // BM-padded segments: block in one expert
    int n0 = by * BN;
    int kb = ks * KCHUNK;

    int tid = threadIdx.x;
    int w = tid >> 6, l = tid & 63;

    int srow = (w << 3) + (l >> 3);                 // 0..31
    int sc   = ((l & 7) ^ ((l >> 3) & 7)) << 3;     // swizzled source chunk (shorts)

    int ta0 = rowtok[row0 + srow];      if (ta0 < 0) ta0 = 0;
    int ta1 = rowtok[row0 + 32 + srow]; if (ta1 < 0) ta1 = 0;
    const short* agA0 = A + (size_t)ta0 * K + kb + sc;
    const short* agA1 = A + (size_t)ta1 * K + kb + sc;
    const short* be = B + (size_t)e * Ntot * K + (size_t)n0 * K + kb;
    const short* agB0 = be + (size_t)(srow     ) * K + sc;
    const short* agB1 = be + (size_t)(srow + 32) * K + sc;
    const short* agB2 = be + (size_t)(srow + 64) * K + sc;
    const short* agB3 = be + (size_t)(srow + 96) * K + sc;

    auto lA_0_0 = (AS3 void*)&As[0][(w << 3)     ][0];
    auto lA_0_1 = (AS3 void*)&As[0][(w << 3) + 32][0];
    auto lA_1_0 = (AS3 void*)&As[1][(w << 3)     ][0];
    auto lA_1_1 = (AS3 void*)&As[1][(w << 3) + 32][0];
    auto lB_0_0 = (AS3 void*)&Bs[0][(w << 3)     ][0];
    auto lB_0_1 = (AS3 void*)&Bs[0][(w << 3) + 32][0];
    auto lB_0_2 = (AS3 void*)&Bs[0][(w << 3) + 64][0];
    auto lB_0_3 = (AS3 void*)&Bs[0][(w << 3) + 96][0];
    auto lB_1_0 = (AS3 void*)&Bs[1][(w << 3)     ][0];
    auto lB_1_1 = (AS3 void*)&Bs[1][(w << 3) + 32][0];
    auto lB_1_2 = (AS3 void*)&Bs[1][(w << 3) + 64][0];
    auto lB_1_3 = (AS3 void*)&Bs[1][(w << 3) + 96][0];

    int mlane = l & 15, qlane = l >> 4;
    int wm = w >> 1, wn = w & 1;
    int c0 = (qlane ^ (mlane & 7)) << 3;
    int c1 = c0 ^ 32;
    int am0 = wm * 32 + mlane, am1 = am0 + 16;
    int bn0 = wn * 64 + mlane, bn1 = bn0 + 16, bn2 = bn0 + 32, bn3 = bn0 + 48;

    f32x4 acc[2][4] = {};

    constexpr int NT = KCHUNK / BKU;       // 8
    STAGE(0);
    STAGE(1);
#pragma unroll 1
    for (int t = 0; t < NT - 2; t += 2) {
        VMCNT(6); BAR();
        COMP(0);
        BAR();
        STAGE(0);
        VMCNT(6); BAR();
        COMP(1);
        BAR();
        if (t + 3 < NT) STAGE(1);
    }
    VMCNT(6); BAR();
    COMP(0);
    BAR();
    VMCNT(0); BAR();
    COMP(1);

    // fp32 atomic partial-sum accumulate (dr zero-initialized upstream)
#pragma unroll
    for (int i = 0; i < 2; i++) {
        int rbase = row0 + wm * 32 + i * 16 + qlane * 4;
#pragma unroll
        for (int j = 0; j < 4; j++) {
            int col = n0 + wn * 64 + j * 16 + mlane;
#pragma unroll
            for (int r = 0; r < 4; r++)
                atomicAdd(&dr[(size_t)(rbase + r) * Ntot + col], acc[i][j][r]);
        }
    }
}

#undef STAGE

// ---------------------------------------------------------------------------
// Up GEMM with FUSED combine1 (A built on the fly from fp32 dr rows) and
// FUSED combine2 (epilogue fp32-atomicAdd into out, gated per row; out
// zero-initialized upstream). Two contributions per output element, fp32
// add is commutative -> deterministic.
// ---------------------------------------------------------------------------
#define STAGE_B(B_) do { \
    GLD16(agB0, lB_##B_##_0); \
    GLD16(agB1, lB_##B_##_1); \
    GLD16(agB2, lB_##B_##_2); \
    GLD16(agB3, lB_##B_##_3); \
    agB0 += BKU; agB1 += BKU; agB2 += BKU; agB3 += BKU; \
} while (0)

#define STAGE_A(B_, kb) do { \
    float8 v0 = *(const float8*)(dr00 + (kb)); \
    float8 v1 = *(const float8*)(dr01 + (kb)); \
    float8 u0 = *(const float8*)(dr10 + (kb)); \
    float8 u1 = *(const float8*)(dr11 + (kb)); \
    short8 o0, o1; \
    _Pragma("unroll") \
    for (int j = 0; j < 8; j++) { \
        o0[j] = f2bf(g00 * v0[j] + g01 * v1[j]); \
        o1[j] = f2bf(g10 * u0[j] + g11 * u1[j]); \
    } \
    *(short8*)&As[B_][srow     ][cl] = o0; \
    *(short8*)&As[B_][srow + 32][cl] = o1; \
} while (0)

__global__ __launch_bounds__(256) void gemm_up_kernel(const float* __restrict__ dr,
                                                      const short* __restrict__ B,
                                                      const int* __restrict__ rowtok,
                                                      const int* __restrict__ rowpos,
                                                      const float* __restrict__ gval,
                                                      const float* __restrict__ grow,
                                                      const int* __restrict__ seg_off,
                                                      float* __restrict__ out)
{
    constexpr int K = DG, Ntot = DIM;
    __shared__ __align__(16) short As[2][BM][BKU];   // 16 KB
    __shared__ __align__(16) short Bs[2][BN][BKU];   // 32 KB

    // XCD pairing: 2176 blocks = 8 chunks of 272; consecutive lids share XCD
    // and (since y = lid/136 is slow) the same B N-tile.
    int d = blockIdx.x;
    int lid = (d & 7) * 272 + (d >> 3);
    int bx = lid % NBLK_M;
    int by = lid / NBLK_M;

    int row0 = bx * BM;
    int total = seg_off[NEXP];
    if (row0 >= total) return;
    int e = 0;
    while (row0 >= seg_off[e + 1]) ++e;
    int n0 = by * BN;

    int tid = threadIdx.x;
    int w = tid >> 6, l = tid & 63;

    int srow = (w << 3) + (l >> 3);                 // 0..31
    int sc   = ((l & 7) ^ ((l >> 3) & 7)) << 3;     // global k-chunk (elements)
    int cl   = (l & 7) << 3;                        // LDS chunk (shorts)

    // A-row metadata, fixed over the K loop
    int t0 = rowtok[row0 + srow];      if (t0 < 0) t0 = 0;
    int t1 = rowtok[row0 + 32 + srow]; if (t1 < 0) t1 = 0;
    int   p00 = rowpos[2 * t0], p01 = rowpos[2 * t0 + 1];
    int   p10 = rowpos[2 * t1], p11 = rowpos[2 * t1 + 1];
    float g00 = gval[2 * t0],   g01 = gval[2 * t0 + 1];
    float g10 = gval[2 * t1],   g11 = gval[2 * t1 + 1];
    const float* dr00 = dr + (size_t)p00 * DG + sc;
    const float* dr01 = dr + (size_t)p01 * DG + sc;
    const float* dr10 = dr + (size_t)p10 * DG + sc;
    const float* dr11 = dr + (size_t)p11 * DG + sc;

    const short* be = B + (size_t)e * Ntot * K + (size_t)n0 * K;
    const short* agB0 = be + (size_t)(srow     ) * K + sc;
    const short* agB1 = be + (size_t)(srow + 32) * K + sc;
    const short* agB2 = be + (size_t)(srow + 64) * K + sc;
    const short* agB3 = be + (size_t)(srow + 96) * K + sc;

    auto lB_0_0 = (AS3 void*)&Bs[0][(w << 3)     ][0];
    auto lB_0_1 = (AS3 void*)&Bs[0][(w << 3) + 32][0];
    auto lB_0_2 = (AS3 void*)&Bs[0][(w << 3) + 64][0];
    auto lB_0_3 = (AS3 void*)&Bs[0][(w << 3) + 96][0];
    auto lB_1_0 = (AS3 void*)&Bs[1][(w << 3)     ][0];
    auto lB_1_1 = (AS3 void*)&Bs[1][(w << 3) + 32][0];
    auto lB_1_2 = (AS3 void*)&Bs[1][(w << 3) + 64][0];
    auto lB_1_3 = (AS3 void*)&Bs[1][(w << 3) + 96][0];

    int mlane = l & 15, qlane = l >> 4;
    int wm = w >> 1, wn = w & 1;
    int c0 = (qlane ^ (mlane & 7)) << 3;
    int c1 = c0 ^ 32;
    int am0 = wm * 32 + mlane, am1 = am0 + 16;
    int bn0 = wn * 64 + mlane, bn1 = bn0 + 16, bn2 = bn0 + 32, bn3 = bn0 + 48;

    f32x4 acc[2][4] = {};

    // K = 256 -> 4 tiles, fully unrolled double-buffer with __syncthreads
    STAGE_A(0, 0); STAGE_B(0);
    __syncthreads();
    STAGE_A(1, BKU); STAGE_B(1);
    COMP(0);
    __syncthreads();
    STAGE_A(0, 2 * BKU); STAGE_B(0);
    COMP(1);
    __syncthreads();
    STAGE_A(1, 3 * BKU); STAGE_B(1);
    COMP(0);
    __syncthreads();
    COMP(1);

    // fused combine2: out[t] += grow[row] * acc   (out zeroed upstream;
    // padding rows rowtok<0 are skipped)
#pragma unroll
    for (int i = 0; i < 2; i++) {
        int rbase = row0 + wm * 32 + i * 16 + qlane * 4;
#pragma unroll
        for (int r = 0; r < 4; r++) {
            int row = rbase + r;
            int tt = rowtok[row];
            if (tt < 0) continue;
            float g = grow[row];
            float* orow = out + (size_t)tt * Ntot + n0 + wn * 64 + mlane;
#pragma unroll
            for (int j = 0; j < 4; j++)
                atomicAdd(orow + j * 16, g * acc[i][j][r]);
        }
    }
}

#undef STAGE_A
#undef STAGE_B
#undef COMP
#undef AS3

extern "C" void kernel_launch(void* const* d_in, const int* in_sizes, int n_in,
                              void* d_out, int out_size, void* d_ws, size_t ws_size,
                              hipStream_t stream) {
    const float* x  = (const float*)d_in[0];
    const float* Wg = (const float*)d_in[1];
    const float* Wd = (const float*)d_in[2];
    const float* Wu = (const float*)d_in[3];
    float* out = (float*)d_out;

    char* p = (char*)d_ws;
    int*   gidx    = (int*)(p + 0);                       // 32768
    float* gval    = (float*)(p + 32768);                 // 32768
    int*   rowtok  = (int*)(p + 65536);                   // 34816
    int*   rowpos  = (int*)(p + 100352);                  // 32768
    int*   seg_off = (int*)(p + 133120);                  // 256 (padded)
    float* grow    = (float*)(p + 133376);                // NROWS*4 = 34816
    short* x_bf    = (short*)(p + 168192);                // 16777216
    short* Wd_bf   = (short*)(p + 168192 + 16777216);     // 8388608
    short* Wu_bf   = Wd_bf + 4194304;                     // 8388608
    float* dr      = (float*)(p + 168192 + 16777216 + 2 * 8388608); // NROWS*DG*4 = 8912896

    gateconv_kernel<<<11808, 256, 0, stream>>>(x, Wg, Wd, Wu, gidx, gval, x_bf, Wd_bf, Wu_bf, out, dr);
    bucket_kernel<<<1, 1024, 0, stream>>>(gidx, gval, rowtok, rowpos, grow, seg_off);
    gemm_down_kernel<<<NBLK_M * 2 * KSPLIT, 256, 0, stream>>>(x_bf, Wd_bf, rowtok, seg_off, dr);
    gemm_up_kernel<<<NBLK_M * (DIM / BN), 256, 0, stream>>>(dr, Wu_bf, rowtok, rowpos, gval, grow, seg_off, out);
}

// Round 5
// 200.461 us; speedup vs baseline: 1.3170x; 1.3170x over previous
//
#include <hip/hip_runtime.h>
#include <stdint.h>

// Problem constants (B=2, L=2048, D=2048, E=8, Dg=256, k=2)
#define T_TOK 4096
#define DIM   2048
#define NEXP  8
#define DG    256
#define TOPK  2

// Up GEMM tiling: 64(M) x 128(N), BKU=64, 4 waves of 32x64.
// Down GEMM tiling: 64(M) x 64(N), BKU=64, 4 waves of 32x32 (544 blocks,
// ~2.1/CU -- occupancy fix for the 32-iteration K loop).
#define BM 64
#define BN 128
#define BND 64
#define BKU 64
#define NROWS  (T_TOK*TOPK + NEXP*BM)   // 8704 padded row capacity
#define NBLK_M (NROWS/BM)               // 136 M-blocks

typedef __attribute__((ext_vector_type(8))) short short8;
typedef __attribute__((ext_vector_type(4))) float f32x4;

static __device__ __forceinline__ short f2bf(float f) {
    union { float f; uint32_t u; } v{f};
    uint32_t r = v.u + 0x7fffu + ((v.u >> 16) & 1u);   // RNE
    return (short)(r >> 16);
}
static __device__ __forceinline__ float b2f(short s) {
    union { uint32_t u; float f; } v{((uint32_t)(unsigned short)s) << 16};
    return v.f;
}

#define GLD16(g, l) \
    __builtin_amdgcn_global_load_lds((const __attribute__((address_space(1))) void*)(g), \
                                     (__attribute__((address_space(3))) void*)(l), 16, 0, 0)

// ---------------------------------------------------------------------------
// Fused gate + x->bf16 + weight fp32->bf16. Blocks [0,1024): gate (one wave
// per token). Blocks [1024, 9216): convW (256 float4 each, exact cover).
// ---------------------------------------------------------------------------
__global__ __launch_bounds__(256) void gateconv_kernel(const float* __restrict__ x,
                                                       const float* __restrict__ Wg,
                                                       const float* __restrict__ Wd,
                                                       const float* __restrict__ Wu,
                                                       int* __restrict__ gidx,
                                                       float* __restrict__ gval,
                                                       short* __restrict__ x_bf,
                                                       short* __restrict__ Wd_bf,
                                                       short* __restrict__ Wu_bf)
{
    if (blockIdx.x >= 1024) {
        // ---- convW path ----
        const int n4 = NEXP * DG * DIM / 4;               // 1048576 per tensor
        int i = (blockIdx.x - 1024) * 256 + threadIdx.x;  // < 2*n4 exactly
        const float* s; short* d; int j;
        if (i < n4) { s = Wd; d = Wd_bf; j = i; }
        else        { s = Wu; d = Wu_bf; j = i - n4; }
        float4 v = ((const float4*)s)[j];
        short4 o;
        o.x = f2bf(v.x); o.y = f2bf(v.y); o.z = f2bf(v.z); o.w = f2bf(v.w);
        ((short4*)d)[j] = o;
        return;
    }

    // ---- gate path ----
    int token = blockIdx.x * 4 + (threadIdx.x >> 6);
    int lane  = threadIdx.x & 63;
    const float4* xr = (const float4*)(x + (size_t)token * DIM);

    float4 xv[8];
#pragma unroll
    for (int i = 0; i < 8; i++) xv[i] = xr[lane + 64 * i];

    short4* xb = (short4*)(x_bf + (size_t)token * DIM);
#pragma unroll
    for (int i = 0; i < 8; i++) {
        short4 o;
        o.x = f2bf(xv[i].x); o.y = f2bf(xv[i].y);
        o.z = f2bf(xv[i].z); o.w = f2bf(xv[i].w);
        xb[lane + 64 * i] = o;
    }

    float acc[NEXP];
#pragma unroll
    for (int e = 0; e < NEXP; e++) {
        const float4* wr = (const float4*)(Wg + e * DIM);
        float a = 0.0f;
#pragma unroll
        for (int i = 0; i < 8; i++) {
            float4 w = wr[lane + 64 * i];
            a += xv[i].x * w.x + xv[i].y * w.y + xv[i].z * w.z + xv[i].w * w.w;
        }
        acc[e] = a;
    }

#pragma unroll
    for (int m = 1; m < 64; m <<= 1) {
#pragma unroll
        for (int e = 0; e < NEXP; e++) acc[e] += __shfl_xor(acc[e], m, 64);
    }

    if (lane == 0) {
        float sg[NEXP];
#pragma unroll
        for (int e = 0; e < NEXP; e++) sg[e] = 1.0f / (1.0f + expf(-acc[e]));
        int i0 = 0;
#pragma unroll
        for (int e = 1; e < NEXP; e++) if (sg[e] > sg[i0]) i0 = e;   // strict >: lowest index wins
        int i1 = (i0 == 0) ? 1 : 0;
#pragma unroll
        for (int e = 0; e < NEXP; e++) if (e != i0 && e != i1 && sg[e] > sg[i1]) i1 = e;
        gidx[2 * token + 0] = i0;
        gidx[2 * token + 1] = i1;
        gval[2 * token + 0] = sg[i0];
        gval[2 * token + 1] = sg[i1];
    }
}

// ---------------------------------------------------------------------------
// Bucket rows by expert (segments padded to BM). Ballot-based counting and
// mask-prefix scatter (order within a segment is arbitrary; rowpos inverts).
// ---------------------------------------------------------------------------
__global__ __launch_bounds__(1024) void bucket_kernel(const int* __restrict__ gidx,
                                                      int* __restrict__ rowtok,
                                                      int* __restrict__ rowpos,
                                                      int* __restrict__ seg_off)
{
    __shared__ int cnt[NEXP];
    __shared__ int cur[NEXP];
    int tid = threadIdx.x, lane = tid & 63;
    if (tid < NEXP) cnt[tid] = 0;
    __syncthreads();

    int e_[8];
#pragma unroll
    for (int r = 0; r < 8; r++) e_[r] = gidx[r * 1024 + tid];

    int mycnt = 0;
#pragma unroll
    for (int r = 0; r < 8; r++) {
        int e = e_[r];
#pragma unroll
        for (int ee = 0; ee < NEXP; ee++) {
            unsigned long long m = __ballot(e == ee);
            if (lane == ee) mycnt += (int)__popcll(m);
        }
    }
    if (lane < NEXP) atomicAdd(&cnt[lane], mycnt);
    __syncthreads();

    if (tid == 0) {
        int o = 0;
        for (int e = 0; e < NEXP; e++) {
            seg_off[e] = o;
            cur[e] = o;
            o += ((cnt[e] + BM - 1) / BM) * BM;
        }
        seg_off[NEXP] = o;
    }
    __syncthreads();

    for (int r = tid; r < NROWS; r += 1024) rowtok[r] = -1;
    __syncthreads();

#pragma unroll
    for (int r = 0; r < 8; r++) {
        int idx = r * 1024 + tid;
        int e = e_[r];
#pragma unroll
        for (int ee = 0; ee < NEXP; ee++) {
            unsigned long long m = __ballot(e == ee);
            if (m == 0) continue;                       // wave-uniform
            int leader = __ffsll((unsigned long long)m) - 1;
            int base = 0;
            if (lane == leader) base = atomicAdd(&cur[ee], (int)__popcll(m));
            base = __shfl(base, leader, 64);
            if (e == ee) {
                int pos = base + (int)__popcll(m & ((1ull << lane) - 1ull));
                rowtok[pos] = idx >> 1;
                rowpos[idx] = pos;
            }
        }
    }
}

// ---------------------------------------------------------------------------
// Down GEMM (bf16 MFMA), counted-vmcnt double-buffer, 64x64 tile:
// grid 136x4 = 544 blocks (~2.1/CU, 8.5 waves/CU -- TLP to hide the stalls
// the 1-block/CU 64x128 version exposed). 32 KB LDS. XCD-chunked so the 4
// N-blocks of one M-tile share an XCD (x_bf fetched once).
// ---------------------------------------------------------------------------
#define AS3 __attribute__((address_space(3)))

#define VMCNT(N) asm volatile("s_waitcnt vmcnt(" #N ")" ::: "memory")
#define BAR()    __builtin_amdgcn_s_barrier()

#define STAGE_D(B_) do { \
    GLD16(agA0, lA_##B_##_0); \
    GLD16(agA1, lA_##B_##_1); \
    GLD16(agB0, lB_##B_##_0); \
    GLD16(agB1, lB_##B_##_1); \
    agA0 += BKU; agA1 += BKU; \
    agB0 += BKU; agB1 += BKU; \
} while (0)

#define COMP_D(B_) do { \
    short8 a00 = *(const short8*)&As[B_][am0][c0]; \
    short8 a10 = *(const short8*)&As[B_][am1][c0]; \
    short8 b00 = *(const short8*)&Bs[B_][bn0][c0]; \
    short8 b10 = *(const short8*)&Bs[B_][bn1][c0]; \
    short8 a01 = *(const short8*)&As[B_][am0][c1]; \
    short8 a11 = *(const short8*)&As[B_][am1][c1]; \
    short8 b01 = *(const short8*)&Bs[B_][bn0][c1]; \
    short8 b11 = *(const short8*)&Bs[B_][bn1][c1]; \
    acc[0][0] = __builtin_amdgcn_mfma_f32_16x16x32_bf16(a00, b00, acc[0][0], 0, 0, 0); \
    acc[0][1] = __builtin_amdgcn_mfma_f32_16x16x32_bf16(a00, b10, acc[0][1], 0, 0, 0); \
    acc[1][0] = __builtin_amdgcn_mfma_f32_16x16x32_bf16(a10, b00, acc[1][0], 0, 0, 0); \
    acc[1][1] = __builtin_amdgcn_mfma_f32_16x16x32_bf16(a10, b10, acc[1][1], 0, 0, 0); \
    acc[0][0] = __builtin_amdgcn_mfma_f32_16x16x32_bf16(a01, b01, acc[0][0], 0, 0, 0); \
    acc[0][1] = __builtin_amdgcn_mfma_f32_16x16x32_bf16(a01, b11, acc[0][1], 0, 0, 0); \
    acc[1][0] = __builtin_amdgcn_mfma_f32_16x16x32_bf16(a11, b01, acc[1][0], 0, 0, 0); \
    acc[1][1] = __builtin_amdgcn_mfma_f32_16x16x32_bf16(a11, b11, acc[1][1], 0, 0, 0); \
} while (0)

__global__ __launch_bounds__(256) void gemm_down_kernel(const short* __restrict__ A,
                                                        const short* __restrict__ B,
                                                        const int* __restrict__ rowtok,
                                                        const int* __restrict__ seg_off,
                                                        short* __restrict__ C)
{
    constexpr int K = DIM, Ntot = DG;
    __shared__ __align__(16) short As[2][BM][BKU];    // 16 KB
    __shared__ __align__(16) short Bs[2][BND][BKU];   // 16 KB

    // XCD chunking: 544 blocks = 8 chunks of 68 consecutive lids. lid is
    // N-minor, so one XCD holds all 4 N-blocks of each of its 17 M-tiles.
    int d = blockIdx.x;
    int lid = (d & 7) * 68 + (d >> 3);
    int bx = lid >> 2, by = lid & 3;

    int row0 = bx * BM;
    int total = seg_off[NEXP];
    if (row0 >= total) return;
    int e = 0;
    while (row0 >= seg_off[e + 1]) ++e;   // BM-padded segments: block in one expert
    int n0 = by * BND;

    int tid = threadIdx.x;
    int w = tid >> 6, l = tid & 63;

    int srow = (w << 3) + (l >> 3);                 // 0..31
    int sc   = ((l & 7) ^ ((l >> 3) & 7)) << 3;     // swizzled source chunk (shorts)

    int ta0 = rowtok[row0 + srow];      if (ta0 < 0) ta0 = 0;
    int ta1 = rowtok[row0 + 32 + srow]; if (ta1 < 0) ta1 = 0;
    const short* agA0 = A + (size_t)ta0 * K + sc;
    const short* agA1 = A + (size_t)ta1 * K + sc;
    const short* be = B + (size_t)e * Ntot * K + (size_t)n0 * K;
    const short* agB0 = be + (size_t)(srow     ) * K + sc;
    const short* agB1 = be + (size_t)(srow + 32) * K + sc;

    auto lA_0_0 = (AS3 void*)&As[0][(w << 3)     ][0];
    auto lA_0_1 = (AS3 void*)&As[0][(w << 3) + 32][0];
    auto lA_1_0 = (AS3 void*)&As[1][(w << 3)     ][0];
    auto lA_1_1 = (AS3 void*)&As[1][(w << 3) + 32][0];
    auto lB_0_0 = (AS3 void*)&Bs[0][(w << 3)     ][0];
    auto lB_0_1 = (AS3 void*)&Bs[0][(w << 3) + 32][0];
    auto lB_1_0 = (AS3 void*)&Bs[1][(w << 3)     ][0];
    auto lB_1_1 = (AS3 void*)&Bs[1][(w << 3) + 32][0];

    int mlane = l & 15, qlane = l >> 4;
    int wm = w >> 1, wn = w & 1;
    int c0 = (qlane ^ (mlane & 7)) << 3;
    int c1 = c0 ^ 32;
    int am0 = wm * 32 + mlane, am1 = am0 + 16;
    int bn0 = wn * 32 + mlane, bn1 = bn0 + 16;

    f32x4 acc[2][2] = {};

    constexpr int NT = K / BKU;            // 32
    STAGE_D(0);
    STAGE_D(1);
#pragma unroll 1
    for (int t = 0; t < NT - 2; t += 2) {
        VMCNT(4); BAR();
        COMP_D(0);
        BAR();
        STAGE_D(0);
        VMCNT(4); BAR();
        COMP_D(1);
        BAR();
        if (t + 3 < NT) STAGE_D(1);
    }
    VMCNT(4); BAR();
    COMP_D(0);
    BAR();
    VMCNT(0); BAR();
    COMP_D(1);

    // epilogue: D layout col = lane&15, row = (lane>>4)*4 + reg  [m89-verified]
#pragma unroll
    for (int i = 0; i < 2; i++) {
        int rbase = row0 + wm * 32 + i * 16 + qlane * 4;
#pragma unroll
        for (int j = 0; j < 2; j++) {
            int col = n0 + wn * 32 + j * 16 + mlane;
#pragma unroll
            for (int r = 0; r < 4; r++)
                C[(size_t)(rbase + r) * Ntot + col] = f2bf(acc[i][j][r]);
        }
    }
}

#undef STAGE_D
#undef COMP_D

// ---------------------------------------------------------------------------
// Up GEMM with FUSED combine1: A rows built on the fly as
//   A[p] = g0*dr[p0] + g1*dr[p1]  (token t = rowtok[p]); bf16 rounding at
// the same point as the old combine1 -> numerically identical.
// B staged via global_load_lds. 4-tile fully-unrolled double buffer.
// ---------------------------------------------------------------------------
#define STAGE_B(B_) do { \
    GLD16(agB0, lB_##B_##_0); \
    GLD16(agB1, lB_##B_##_1); \
    GLD16(agB2, lB_##B_##_2); \
    GLD16(agB3, lB_##B_##_3); \
    agB0 += BKU; agB1 += BKU; agB2 += BKU; agB3 += BKU; \
} while (0)

#define STAGE_A(B_, kb) do { \
    short8 v0 = *(const short8*)(dr00 + (kb)); \
    short8 v1 = *(const short8*)(dr01 + (kb)); \
    short8 u0 = *(const short8*)(dr10 + (kb)); \
    short8 u1 = *(const short8*)(dr11 + (kb)); \
    short8 o0, o1; \
    _Pragma("unroll") \
    for (int j = 0; j < 8; j++) { \
        o0[j] = f2bf(g00 * b2f(v0[j]) + g01 * b2f(v1[j])); \
        o1[j] = f2bf(g10 * b2f(u0[j]) + g11 * b2f(u1[j])); \
    } \
    *(short8*)&As[B_][srow     ][cl] = o0; \
    *(short8*)&As[B_][srow + 32][cl] = o1; \
} while (0)

#define COMP(B_) do { \
    short8 a00 = *(const short8*)&As[B_][am0][c0]; \
    short8 a10 = *(const short8*)&As[B_][am1][c0]; \
    short8 b00 = *(const short8*)&Bs[B_][bn0][c0]; \
    short8 b10 = *(const short8*)&Bs[B_][bn1][c0]; \
    short8 b20 = *(const short8*)&Bs[B_][bn2][c0]; \
    short8 b30 = *(const short8*)&Bs[B_][bn3][c0]; \
    short8 a01 = *(const short8*)&As[B_][am0][c1]; \
    short8 a11 = *(const short8*)&As[B_][am1][c1]; \
    short8 b01 = *(const short8*)&Bs[B_][bn0][c1]; \
    short8 b11 = *(const short8*)&Bs[B_][bn1][c1]; \
    short8 b21 = *(const short8*)&Bs[B_][bn2][c1]; \
    short8 b31 = *(const short8*)&Bs[B_][bn3][c1]; \
    acc[0][0] = __builtin_amdgcn_mfma_f32_16x16x32_bf16(a00, b00, acc[0][0], 0, 0, 0); \
    acc[0][1] = __builtin_amdgcn_mfma_f32_16x16x32_bf16(a00, b10, acc[0][1], 0, 0, 0); \
    acc[0][2] = __builtin_amdgcn_mfma_f32_16x16x32_bf16(a00, b20, acc[0][2], 0, 0, 0); \
    acc[0][3] = __builtin_amdgcn_mfma_f32_16x16x32_bf16(a00, b30, acc[0][3], 0, 0, 0); \
    acc[1][0] = __builtin_amdgcn_mfma_f32_16x16x32_bf16(a10, b00, acc[1][0], 0, 0, 0); \
    acc[1][1] = __builtin_amdgcn_mfma_f32_16x16x32_bf16(a10, b10, acc[1][1], 0, 0, 0); \
    acc[1][2] = __builtin_amdgcn_mfma_f32_16x16x32_bf16(a10, b20, acc[1][2], 0, 0, 0); \
    acc[1][3] = __builtin_amdgcn_mfma_f32_16x16x32_bf16(a10, b30, acc[1][3], 0, 0, 0); \
    acc[0][0] = __builtin_amdgcn_mfma_f32_16x16x32_bf16(a01, b01, acc[0][0], 0, 0, 0); \
    acc[0][1] = __builtin_amdgcn_mfma_f32_16x16x32_bf16(a01, b11, acc[0][1], 0, 0, 0); \
    acc[0][2] = __builtin_amdgcn_mfma_f32_16x16x32_bf16(a01, b21, acc[0][2], 0, 0, 0); \
    acc[0][3] = __builtin_amdgcn_mfma_f32_16x16x32_bf16(a01, b31, acc[0][3], 0, 0, 0); \
    acc[1][0] = __builtin_amdgcn_mfma_f32_16x16x32_bf16(a11, b01, acc[1][0], 0, 0, 0); \
    acc[1][1] = __builtin_amdgcn_mfma_f32_16x16x32_bf16(a11, b11, acc[1][1], 0, 0, 0); \
    acc[1][2] = __builtin_amdgcn_mfma_f32_16x16x32_bf16(a11, b21, acc[1][2], 0, 0, 0); \
    acc[1][3] = __builtin_amdgcn_mfma_f32_16x16x32_bf16(a11, b31, acc[1][3], 0, 0, 0); \
} while (0)

__global__ __launch_bounds__(256) void gemm_up_kernel(const short* __restrict__ dr,
                                                      const short* __restrict__ B,
                                                      const int* __restrict__ rowtok,
                                                      const int* __restrict__ rowpos,
                                                      const float* __restrict__ gval,
                                                      const int* __restrict__ seg_off,
                                                      short* __restrict__ C)
{
    constexpr int K = DG, Ntot = DIM;
    __shared__ __align__(16) short As[2][BM][BKU];   // 16 KB
    __shared__ __align__(16) short Bs[2][BN][BKU];   // 32 KB

    // XCD pairing: 2176 blocks = 8 chunks of 272; consecutive lids share XCD
    // and (since y = lid/136 is slow) the same B N-tile.
    int d = blockIdx.x;
    int lid = (d & 7) * 272 + (d >> 3);
    int bx = lid % NBLK_M;
    int by = lid / NBLK_M;

    int row0 = bx * BM;
    int total = seg_off[NEXP];
    if (row0 >= total) return;
    int e = 0;
    while (row0 >= seg_off[e + 1]) ++e;
    int n0 = by * BN;

    int tid = threadIdx.x;
    int w = tid >> 6, l = tid & 63;

    int srow = (w << 3) + (l >> 3);                 // 0..31
    int sc   = ((l & 7) ^ ((l >> 3) & 7)) << 3;     // global k-chunk (shorts)
    int cl   = (l & 7) << 3;                        // LDS chunk (shorts)

    // A-row metadata, fixed over the K loop
    int t0 = rowtok[row0 + srow];      if (t0 < 0) t0 = 0;
    int t1 = rowtok[row0 + 32 + srow]; if (t1 < 0) t1 = 0;
    int   p00 = rowpos[2 * t0], p01 = rowpos[2 * t0 + 1];
    int   p10 = rowpos[2 * t1], p11 = rowpos[2 * t1 + 1];
    float g00 = gval[2 * t0],   g01 = gval[2 * t0 + 1];
    float g10 = gval[2 * t1],   g11 = gval[2 * t1 + 1];
    const short* dr00 = dr + (size_t)p00 * DG + sc;
    const short* dr01 = dr + (size_t)p01 * DG + sc;
    const short* dr10 = dr + (size_t)p10 * DG + sc;
    const short* dr11 = dr + (size_t)p11 * DG + sc;

    const short* be = B + (size_t)e * Ntot * K + (size_t)n0 * K;
    const short* agB0 = be + (size_t)(srow     ) * K + sc;
    const short* agB1 = be + (size_t)(srow + 32) * K + sc;
    const short* agB2 = be + (size_t)(srow + 64) * K + sc;
    const short* agB3 = be + (size_t)(srow + 96) * K + sc;

    auto lB_0_0 = (AS3 void*)&Bs[0][(w << 3)     ][0];
    auto lB_0_1 = (AS3 void*)&Bs[0][(w << 3) + 32][0];
    auto lB_0_2 = (AS3 void*)&Bs[0][(w << 3) + 64][0];
    auto lB_0_3 = (AS3 void*)&Bs[0][(w << 3) + 96][0];
    auto lB_1_0 = (AS3 void*)&Bs[1][(w << 3)     ][0];
    auto lB_1_1 = (AS3 void*)&Bs[1][(w << 3) + 32][0];
    auto lB_1_2 = (AS3 void*)&Bs[1][(w << 3) + 64][0];
    auto lB_1_3 = (AS3 void*)&Bs[1][(w << 3) + 96][0];

    int mlane = l & 15, qlane = l >> 4;
    int wm = w >> 1, wn = w & 1;
    int c0 = (qlane ^ (mlane & 7)) << 3;
    int c1 = c0 ^ 32;
    int am0 = wm * 32 + mlane, am1 = am0 + 16;
    int bn0 = wn * 64 + mlane, bn1 = bn0 + 16, bn2 = bn0 + 32, bn3 = bn0 + 48;

    f32x4 acc[2][4] = {};

    // K = 256 -> 4 tiles, fully unrolled double-buffer with __syncthreads
    STAGE_A(0, 0); STAGE_B(0);
    __syncthreads();
    STAGE_A(1, BKU); STAGE_B(1);
    COMP(0);
    __syncthreads();
    STAGE_A(0, 2 * BKU); STAGE_B(0);
    COMP(1);
    __syncthreads();
    STAGE_A(1, 3 * BKU); STAGE_B(1);
    COMP(0);
    __syncthreads();
    COMP(1);

#pragma unroll
    for (int i = 0; i < 2; i++) {
        int rbase = row0 + wm * 32 + i * 16 + qlane * 4;
#pragma unroll
        for (int j = 0; j < 4; j++) {
            int col = n0 + wn * 64 + j * 16 + mlane;
#pragma unroll
            for (int r = 0; r < 4; r++)
                C[(size_t)(rbase + r) * Ntot + col] = f2bf(acc[i][j][r]);
        }
    }
}

#undef STAGE_A
#undef STAGE_B
#undef COMP
#undef AS3

// ---------------------------------------------------------------------------
// Combine up rows -> final output (fp32). short4-vectorized.
// ---------------------------------------------------------------------------
__global__ __launch_bounds__(256) void combine2_kernel(const short* __restrict__ ur,
                                                       const int* __restrict__ rowpos,
                                                       const float* __restrict__ gval,
                                                       float* __restrict__ out)
{
    int i = blockIdx.x * 256 + threadIdx.x;       // i < T*D/4
    int t = i >> 9;                               // D/4 = 512
    int c = (i & 511) * 4;
    int   p0 = rowpos[2 * t], p1 = rowpos[2 * t + 1];
    float g0 = gval[2 * t],   g1 = gval[2 * t + 1];
    short4 u0 = *(const short4*)&ur[(size_t)p0 * DIM + c];
    short4 u1 = *(const short4*)&ur[(size_t)p1 * DIM + c];
    float4 o;
    o.x = g0 * b2f(u0.x) + g1 * b2f(u1.x);
    o.y = g0 * b2f(u0.y) + g1 * b2f(u1.y);
    o.z = g0 * b2f(u0.z) + g1 * b2f(u1.z);
    o.w = g0 * b2f(u0.w) + g1 * b2f(u1.w);
    *(float4*)&out[(size_t)t * DIM + c] = o;
}

extern "C" void kernel_launch(void* const* d_in, const int* in_sizes, int n_in,
                              void* d_out, int out_size, void* d_ws, size_t ws_size,
                              hipStream_t stream) {
    const float* x  = (const float*)d_in[0];
    const float* Wg = (const float*)d_in[1];
    const float* Wd = (const float*)d_in[2];
    const float* Wu = (const float*)d_in[3];
    float* out = (float*)d_out;

    char* p = (char*)d_ws;
    int*   gidx    = (int*)(p + 0);                       // 32768
    float* gval    = (float*)(p + 32768);                 // 32768
    int*   rowtok  = (int*)(p + 65536);                   // 34816
    int*   rowpos  = (int*)(p + 100352);                  // 32768
    int*   seg_off = (int*)(p + 133120);                  // 256 (padded)
    short* x_bf    = (short*)(p + 133376);                // 16777216
    short* Wd_bf   = (short*)(p + 133376 + 16777216);     // 8388608
    short* Wu_bf   = Wd_bf + 4194304;                     // 8388608
    short* dr_bf   = Wu_bf + 4194304;                     // NROWS*DG*2  = 4456448
    short* ur_bf   = dr_bf + (size_t)NROWS * DG;          // NROWS*DIM*2 = 35651584

    gateconv_kernel<<<9216, 256, 0, stream>>>(x, Wg, Wd, Wu, gidx, gval, x_bf, Wd_bf, Wu_bf);
    bucket_kernel<<<1, 1024, 0, stream>>>(gidx, rowtok, rowpos, seg_off);
    gemm_down_kernel<<<NBLK_M * (DG / BND), 256, 0, stream>>>(x_bf, Wd_bf, rowtok, seg_off, dr_bf);
    gemm_up_kernel<<<NBLK_M * (DIM / BN), 256, 0, stream>>>(dr_bf, Wu_bf, rowtok, rowpos, gval, seg_off, ur_bf);
    combine2_kernel<<<T_TOK * DIM / 4 / 256, 256, 0, stream>>>(ur_bf, rowpos, gval, out);
}